// Round 7
// baseline (644.157 us; speedup 1.0000x reference)
//
#include <hip/hip_runtime.h>

// LogicVAE: graph-GRU VAE encoder. B=2048,N=32,V=10,H=256,Z=64.
// gm[b,n] = sigmoid(h@w_gate+b_gate)*(h@w_map) is a pure function of the FINAL
// hidden[b,n] (adj strictly upper-tri), so it's computed once per node.
// R12: attack LATENCY, not traffic. Evidence: per-step wall = 14us for ~2-3us
// of work; MfmaUtil 7%, VALU 17%, HBM 2.8/6.3 TB/s, L2 set tiny -> nothing
// saturated = latency-bound. At 1024thr the allocator caps VGPR=64 (8 w/EU
// target) -> only ~2-3 weight loads in flight -> serial ~500cy per K-chunk.
// (Pins at 192 regs spilled in R11; waves_per_eu never took effect. Dead.)
//  - 512 threads x 256 blocks: natural VGPR=128 (measured R7/R11) -> deep
//    load pipelining; afrag/hfrag hoisted to regs (32) shared across chains
//  - phase A's serial gm gather folded INTO phase D (rows <=v-2 exist then);
//    finish-A after the barrier adds only row v-1. Gather overlaps D's MFMA
//    weight streams instead of sitting alone between barriers.
//  - BT=8, gmAll in LDS 128KB, weights streamed from L2 (no pins)
// LDS: 131072+8448+8448+1024+1024+3072+1024 = 154112 B (1 blk/CU, 8 waves).

#define BB 2048
#define NN 32
#define VV 10
#define HH 256
#define ZZ 64
#define BT 8      // batches per block
#define KC 8      // K chunks: 256/32
#define NT1 48    // 768/16 col tiles (w_hh)
#define NT2 32    // 512/16 col tiles (w_gate||w_map)
#define WHH_ELEMS (NT1 * KC * 64 * 8)             // 196608 ushorts (384 KB)
#define WGM_ELEMS (NT2 * KC * 64 * 8)             // 131072 ushorts (256 KB)

typedef __attribute__((ext_vector_type(8))) short frag8;            // 8 bf16 (4 VGPR)
typedef __attribute__((ext_vector_type(4))) float facc4;            // MFMA accum
typedef __attribute__((ext_vector_type(4))) unsigned short us4;     // 8B LDS load

__device__ __forceinline__ float bf2f(unsigned short u) {
    unsigned int x = ((unsigned int)u) << 16;
    return __builtin_bit_cast(float, x);
}
__device__ __forceinline__ unsigned short f2bf(float f) {
    unsigned int x = __builtin_bit_cast(unsigned int, f);
    x += 0x7FFFu + ((x >> 16) & 1u);
    return (unsigned short)(x >> 16);
}
__device__ __forceinline__ float sigm(float x) { return 1.0f / (1.0f + __expf(-x)); }
__device__ __forceinline__ float ldv(const float* p, size_t i) { return p[i]; }
__device__ __forceinline__ float ldv(const unsigned short* p, size_t i) { return bf2f(p[i]); }
__device__ __forceinline__ void stv(float* p, size_t i, float v) { p[i] = v; }
__device__ __forceinline__ void stv(unsigned short* p, size_t i, float v) { p[i] = f2bf(v); }

// flag=1 => buffers are fp32, flag=0 => bf16. Integer-only tests (fast-math safe).
__global__ void detect_dtype(const unsigned short* __restrict__ w, int* flag) {
    __shared__ int zc, bc;
    if (threadIdx.x == 0) { zc = 0; bc = 0; }
    __syncthreads();
    int z = 0, b = 0;
    for (int i = threadIdx.x; i < 2048; i += 256) {
        unsigned short lo = w[2 * i];            // fp32: low mantissa half / bf16: a value
        if (lo == 0) z++;                        // bf16-rounded fp32 storage => all zero
        unsigned e = (lo >> 7) & 0xFFu;          // bf16 exponent field
        if (e >= 0x86u) b++;                     // |x|>=128 or NaN: impossible for N(0,.05) bf16
    }
    atomicAdd(&zc, z); atomicAdd(&bc, b);
    __syncthreads();
    if (threadIdx.x == 0) *flag = (bc > 0 || zc > 512) ? 1 : 0;
}

// Repack w_hh (256x768) and w_gate||w_map (256x512) into bf16 MFMA B-fragment
// order: frag f=jt*KC+kc; elem[(f*64+lane)*8+j] = W[kc*32+(lane>>4)*8+j][jt*16+(lane&15)]
// Tail threads build wihG[10][768] = fp32(w_ih + b_ih) folded table.
template <typename T>
__global__ void repack_weights(const T* __restrict__ w_hh,
                               const T* __restrict__ w_gate,
                               const T* __restrict__ w_map,
                               const T* __restrict__ w_ih,
                               const T* __restrict__ b_ih,
                               unsigned short* __restrict__ whh_p,
                               unsigned short* __restrict__ wgm_p,
                               float* __restrict__ wihG,
                               const int* __restrict__ flag, int want) {
    if (*flag != want) return;
    int t = blockIdx.x * blockDim.x + threadIdx.x;
    int lane = t & 63;
    int frag = t >> 6;                  // 0..759
    int kbase = (lane >> 4) * 8;
    if (frag < NT1 * KC) {
        int jt = frag / KC, kc = frag % KC;
        int col = jt * 16 + (lane & 15);
        unsigned short* dst = whh_p + ((size_t)frag * 64 + lane) * 8;
        #pragma unroll
        for (int j = 0; j < 8; ++j)
            dst[j] = f2bf(ldv(w_hh, (size_t)(kc * 32 + kbase + j) * 768 + col));
    } else if (frag < (NT1 + NT2) * KC) {
        int f2 = frag - NT1 * KC;
        int jt = f2 / KC, kc = f2 % KC;
        int col = jt * 16 + (lane & 15);
        unsigned short* dst = wgm_p + ((size_t)f2 * 64 + lane) * 8;
        #pragma unroll
        for (int j = 0; j < 8; ++j) {
            int k = kc * 32 + kbase + j;
            dst[j] = f2bf((col < HH) ? ldv(w_gate, (size_t)k * HH + col)
                                     : ldv(w_map, (size_t)k * HH + (col - HH)));
        }
    } else {
        int idx = t - (NT1 + NT2) * KC * 64;     // 0..7679 with grid=190
        if (idx < VV * 768) {
            int c = idx % 768;
            wihG[idx] = ldv(w_ih, (size_t)idx) + ldv(b_ih, (size_t)c);
        }
    }
}

template <typename T>
__global__ __launch_bounds__(512) void vae_main(
    const T* __restrict__ adj,
    const int* __restrict__ ntypes,
    const T* __restrict__ b_hh,
    const T* __restrict__ b_gate,
    const T* __restrict__ w_mu,
    const T* __restrict__ b_mu,
    const T* __restrict__ w_std,
    const T* __restrict__ b_std,
    const unsigned short* __restrict__ whh_p,
    const unsigned short* __restrict__ wgm_p,
    const float* __restrict__ wihG,
    T* __restrict__ out,
    const int* __restrict__ flag, int want)
{
    if (*flag != want) return;

    __shared__ __align__(16) unsigned short gmAll[BT][NN][HH]; // gm state (128 KB)
    __shared__ __align__(16) unsigned short aggbf[16][264];    // MFMA A src rows 0..7
    __shared__ __align__(16) unsigned short hnew[16][264];     // MFMA A src rows 0..7
    __shared__ unsigned int  amask[BT][NN];                    // adj bitmasks (1 KB)
    __shared__ int           ntva[BT][NN];                     // node types (1 KB)
    __shared__ __align__(16) float bhhL[768];                  // b_hh (3 KB)
    __shared__ float bgL[HH];                                  // b_gate (1 KB)

    // fp32 agg overlays the dead rows 8..15 (those MFMA C-rows are discarded;
    // garbage A-rows 8..15 only pollute discarded C-rows 8..15).
    float* const aggA = (float*)&aggbf[8][0];   // bi 0..3: 4x256 fp32 (4 KB)
    float* const aggB = (float*)&hnew[8][0];    // bi 4..7

    const int tid  = threadIdx.x;
    const int lane = tid & 63;
    const int w    = tid >> 6;          // wave 0..7
    const int b0   = blockIdx.x * BT;

    const frag8* whh8 = (const frag8*)whh_p;
    const frag8* wgm8 = (const frag8*)wgm_p;

    // ---- one-time preload (512 threads) ----
    if (tid < 256) {                         // adj -> bitmask (adj is exactly {0,1})
        int bi = tid >> 5, vv = tid & 31;
        unsigned m = 0;
        for (int n = 0; n < NN; ++n)
            if (ldv(adj, ((size_t)(b0 + bi) * NN + n) * NN + vv) != 0.0f) m |= (1u << n);
        amask[bi][vv] = m;
    } else {
        int idx = tid - 256;
        int bi = idx >> 5, vv = idx & 31;
        ntva[bi][vv] = ntypes[(b0 + bi) * NN + vv];
    }
    for (int i = tid; i < 768; i += 512) bhhL[i] = ldv(b_hh, i);
    if (tid < HH) bgL[tid] = ldv(b_gate, tid);
    __syncthreads();

    // A-partial for batch w, step v: covers neighbor rows n <= v-2 (gathered
    // during the previous step's D phase); row v-1 added in finish-A.
    float pa0 = 0.f, pa1 = 0.f, pa2 = 0.f, pa3 = 0.f;
    const int h4 = lane * 4;

    for (int v = 0; v < NN; ++v) {
        // ---- finish-A: add newest gm row (v-1) if adjacent; publish agg ----
        {
            const int bi = w;
            if (v > 0 && ((amask[bi][v] >> (v - 1)) & 1u)) {
                const us4 g = *(const us4*)(&gmAll[bi][v - 1][0] + h4);
                pa0 += bf2f(g.x); pa1 += bf2f(g.y);
                pa2 += bf2f(g.z); pa3 += bf2f(g.w);
            }
            float* ap = (bi < 4) ? (aggA + bi * 256) : (aggB + (bi - 4) * 256);
            *(float4*)(ap + h4) = make_float4(pa0, pa1, pa2, pa3);
            ushort4 ab; ab.x = f2bf(pa0); ab.y = f2bf(pa1);
            ab.z = f2bf(pa2); ab.w = f2bf(pa3);
            *(ushort4*)&aggbf[bi][h4] = ab;
        }
        __syncthreads();

        // ---- B: gh = agg @ w_hh (2 triplets/wave, streamed) + GRU -> hnew
        {
            frag8 afrag[KC];                              // hoisted: shared by 6 chains
            #pragma unroll
            for (int kc = 0; kc < KC; ++kc)
                afrag[kc] = *(const frag8*)&aggbf[lane & 15][kc * 32 + (lane >> 4) * 8];

            #pragma unroll
            for (int s = 0; s < 2; ++s) {
                const int t = w + 8 * s;                  // triplet cols t,t+16,t+32
                const int col = t * 16 + (lane & 15);
                const int q = lane >> 4;                  // C row = 4q+i, valid q<2

                facc4 aR = {0.f, 0.f, 0.f, 0.f};
                facc4 aZ = {0.f, 0.f, 0.f, 0.f};
                facc4 aN = {0.f, 0.f, 0.f, 0.f};
                const frag8* pR = whh8 + (size_t)(t     ) * (KC * 64) + lane;
                const frag8* pZ = whh8 + (size_t)(t + 16) * (KC * 64) + lane;
                const frag8* pN = whh8 + (size_t)(t + 32) * (KC * 64) + lane;
                #pragma unroll
                for (int kc = 0; kc < KC; ++kc) {
                    aR = __builtin_amdgcn_mfma_f32_16x16x32_bf16(afrag[kc], pR[kc * 64], aR, 0, 0, 0);
                    aZ = __builtin_amdgcn_mfma_f32_16x16x32_bf16(afrag[kc], pZ[kc * 64], aZ, 0, 0, 0);
                    aN = __builtin_amdgcn_mfma_f32_16x16x32_bf16(afrag[kc], pN[kc * 64], aN, 0, 0, 0);
                }
                if (q < 2) {
                    const float bhr = bhhL[col], bhz = bhhL[col + 256], bhn = bhhL[col + 512];
                    const float* ap = (q == 0) ? aggA : aggB;
                    #pragma unroll
                    for (int i = 0; i < 4; ++i) {
                        const float* wr = wihG + (size_t)ntva[4 * q + i][v] * 768 + col;
                        const float r = sigm(wr[0]   + aR[i] + bhr);
                        const float z = sigm(wr[256] + aZ[i] + bhz);
                        const float n = tanhf(wr[512] + r * (aN[i] + bhn));
                        hnew[4 * q + i][col] = f2bf((1.f - z) * n + z * ap[i * 256 + col]);
                    }
                }
            }
        }
        __syncthreads();

        // ---- D (+ overlapped A-gather for step v+1) ----
        {
            // A-partial gather first: independent LDS reads (rows <= v-1 of
            // gmAll, none touched by D's row-v writes) overlap the D streams.
            pa0 = pa1 = pa2 = pa3 = 0.f;
            if (v + 1 < NN) {
                unsigned m = amask[w][v + 1] & ((1u << v) - 1u);  // bits n <= v-1
                const unsigned short* rb = &gmAll[w][0][0] + h4;
                while (m) {                  // 2-wide to keep 2 ds_reads in flight
                    const int n0 = __builtin_ctz(m); m &= m - 1;
                    const us4 g0 = *(const us4*)(rb + n0 * HH);
                    if (m) {
                        const int n1 = __builtin_ctz(m); m &= m - 1;
                        const us4 g1 = *(const us4*)(rb + n1 * HH);
                        pa0 += bf2f(g0.x) + bf2f(g1.x);
                        pa1 += bf2f(g0.y) + bf2f(g1.y);
                        pa2 += bf2f(g0.z) + bf2f(g1.z);
                        pa3 += bf2f(g0.w) + bf2f(g1.w);
                    } else {
                        pa0 += bf2f(g0.x); pa1 += bf2f(g0.y);
                        pa2 += bf2f(g0.z); pa3 += bf2f(g0.w);
                    }
                }
            }

            frag8 hfrag[KC];                              // hoisted: shared by 4 chains
            #pragma unroll
            for (int kc = 0; kc < KC; ++kc)
                hfrag[kc] = *(const frag8*)&hnew[lane & 15][kc * 32 + (lane >> 4) * 8];

            facc4 aG0 = {0.f, 0.f, 0.f, 0.f};
            facc4 aG1 = {0.f, 0.f, 0.f, 0.f};
            facc4 aM0 = {0.f, 0.f, 0.f, 0.f};
            facc4 aM1 = {0.f, 0.f, 0.f, 0.f};
            const frag8* pG0 = wgm8 + (size_t)(w     ) * (KC * 64) + lane;
            const frag8* pG1 = wgm8 + (size_t)(w +  8) * (KC * 64) + lane;
            const frag8* pM0 = wgm8 + (size_t)(w + 16) * (KC * 64) + lane;
            const frag8* pM1 = wgm8 + (size_t)(w + 24) * (KC * 64) + lane;
            #pragma unroll
            for (int kc = 0; kc < KC; ++kc) {
                aG0 = __builtin_amdgcn_mfma_f32_16x16x32_bf16(hfrag[kc], pG0[kc * 64], aG0, 0, 0, 0);
                aG1 = __builtin_amdgcn_mfma_f32_16x16x32_bf16(hfrag[kc], pG1[kc * 64], aG1, 0, 0, 0);
                aM0 = __builtin_amdgcn_mfma_f32_16x16x32_bf16(hfrag[kc], pM0[kc * 64], aM0, 0, 0, 0);
                aM1 = __builtin_amdgcn_mfma_f32_16x16x32_bf16(hfrag[kc], pM1[kc * 64], aM1, 0, 0, 0);
            }
            const int q = lane >> 4;
            if (q < 2) {
                const int c0 = w * 16 + (lane & 15);       // gate w   x map w+16
                const int c1 = (w + 8) * 16 + (lane & 15); // gate w+8 x map w+24
                const float bg0 = bgL[c0], bg1 = bgL[c1];
                #pragma unroll
                for (int i = 0; i < 4; ++i) {
                    gmAll[4 * q + i][v][c0] = f2bf(sigm(aG0[i] + bg0) * aM0[i]);
                    gmAll[4 * q + i][v][c1] = f2bf(sigm(aG1[i] + bg1) * aM1[i]);
                }
            }
        }
        __syncthreads();   // gmAll row v / hnew ready for next finish-A / epilogue
    }

    // ---- Epilogue: hg = h_new(v=31) (in hnew LDS); mu/sigma = hg@w_mu/std + b
    {
        const int bi = w, z = lane;                      // 1 wave per batch
        float am = 0.f, as = 0.f;
        #pragma unroll 4
        for (int h = 0; h < HH; ++h) {
            const float hv = bf2f(hnew[bi][h]);          // LDS broadcast
            am += hv * ldv(w_mu, (size_t)h * ZZ + z);
            as += hv * ldv(w_std, (size_t)h * ZZ + z);
        }
        stv(out, (size_t)(b0 + bi) * ZZ + z, am + ldv(b_mu, z));
        stv(out, (size_t)BB * ZZ + (size_t)(b0 + bi) * ZZ + z, as + ldv(b_std, z));
    }
}

extern "C" void kernel_launch(void* const* d_in, const int* in_sizes, int n_in,
                              void* d_out, int out_size, void* d_ws, size_t ws_size,
                              hipStream_t stream)
{
    unsigned short* whh_p = (unsigned short*)d_ws;
    unsigned short* wgm_p = whh_p + WHH_ELEMS;
    float* wihG = (float*)(wgm_p + WGM_ELEMS);             // byte off 655360 (16B aligned)

    // dtype flag lives in the last aligned 4 bytes of ws
    size_t flag_off = (ws_size >= 8) ? ((ws_size - 4) & ~(size_t)3) : 0;
    int* flag = (int*)((char*)d_ws + flag_off);

    detect_dtype<<<dim3(1), 256, 0, stream>>>((const unsigned short*)d_in[2], flag);

    // 190 blocks = 640 weight frags * 64 lanes + 7680 wihG elems, exactly
    repack_weights<float><<<dim3(190), 256, 0, stream>>>(
        (const float*)d_in[3], (const float*)d_in[6], (const float*)d_in[8],
        (const float*)d_in[2], (const float*)d_in[4],
        whh_p, wgm_p, wihG, flag, 1);
    repack_weights<unsigned short><<<dim3(190), 256, 0, stream>>>(
        (const unsigned short*)d_in[3], (const unsigned short*)d_in[6],
        (const unsigned short*)d_in[8], (const unsigned short*)d_in[2],
        (const unsigned short*)d_in[4],
        whh_p, wgm_p, wihG, flag, 0);

    vae_main<float><<<dim3(BB / BT), 512, 0, stream>>>(
        (const float*)d_in[0], (const int*)d_in[1],
        (const float*)d_in[5], (const float*)d_in[7],
        (const float*)d_in[9], (const float*)d_in[10],
        (const float*)d_in[11], (const float*)d_in[12],
        whh_p, wgm_p, wihG, (float*)d_out, flag, 1);
    vae_main<unsigned short><<<dim3(BB / BT), 512, 0, stream>>>(
        (const unsigned short*)d_in[0], (const int*)d_in[1],
        (const unsigned short*)d_in[5], (const unsigned short*)d_in[7],
        (const unsigned short*)d_in[9], (const unsigned short*)d_in[10],
        (const unsigned short*)d_in[11], (const unsigned short*)d_in[12],
        whh_p, wgm_p, wihG, (unsigned short*)d_out, flag, 0);
}

// Round 8
// 539.848 us; speedup vs baseline: 1.1932x; 1.1932x over previous
//
#include <hip/hip_runtime.h>

// LogicVAE: graph-GRU VAE encoder. B=2048,N=32,V=10,H=256,Z=64.
// gm[b,n] = sigmoid(h@w_gate+b_gate)*(h@w_map) is a pure function of the FINAL
// hidden[b,n] (adj strictly upper-tri), so it's computed once per node.
// R13 = R9 (best: 456us steady; 1024thr/16 waves, BT=8, gmAll in LDS, wgm
// asm-pinned in AGPRs) + dissolve phase A:
//  - R7/R11/R12 proved 8-wave blocks lose to 16-wave regardless of ILP; R9's
//    pin is the only change that ever cut FETCH+dur together. Keep both.
//  - step is phase-latency-bound (14.2us vs ~4us of component work; nothing
//    saturated). A's serial gather (avg ~2 rows @12% adj density) moves INTO
//    phase D (rows <=v-2 don't conflict with D's row-v writes), where it
//    hides under the pinned-MFMA chain. finish-A (row v-1 add + publish)
//    is all that remains between D's barrier and B.
//  - wihG's 12 scattered loads issued BEFORE B's MFMA chain (hide ~200cy).
//  - adj preload via nontemporal loads (17MB one-shot, keep L2 for weights).
// LDS: 131072+8448+8448+1024+1024+3072+1024 = 154112 B (1 blk/CU, 16 waves).
// Watch: VGPR must stay 64 / WRITE ~80MB (else spill); steady >=450 kills
// the A-window theory.

#define BB 2048
#define NN 32
#define VV 10
#define HH 256
#define ZZ 64
#define BT 8      // batches per block
#define KC 8      // K chunks: 256/32
#define NT1 48    // 768/16 col tiles (w_hh)
#define NT2 32    // 512/16 col tiles (w_gate||w_map)
#define WHH_ELEMS (NT1 * KC * 64 * 8)             // 196608 ushorts (384 KB)
#define WGM_ELEMS (NT2 * KC * 64 * 8)             // 131072 ushorts (256 KB)

typedef __attribute__((ext_vector_type(8))) short frag8;            // 8 bf16 (4 VGPR)
typedef __attribute__((ext_vector_type(4))) float facc4;            // MFMA accum
typedef __attribute__((ext_vector_type(4))) unsigned short us4;     // 8B LDS load
typedef __attribute__((ext_vector_type(4))) unsigned int ui4;       // asm-pin carrier

__device__ __forceinline__ float bf2f(unsigned short u) {
    unsigned int x = ((unsigned int)u) << 16;
    return __builtin_bit_cast(float, x);
}
__device__ __forceinline__ unsigned short f2bf(float f) {
    unsigned int x = __builtin_bit_cast(unsigned int, f);
    x += 0x7FFFu + ((x >> 16) & 1u);
    return (unsigned short)(x >> 16);
}
__device__ __forceinline__ float sigm(float x) { return 1.0f / (1.0f + __expf(-x)); }
__device__ __forceinline__ float ldv(const float* p, size_t i) { return p[i]; }
__device__ __forceinline__ float ldv(const unsigned short* p, size_t i) { return bf2f(p[i]); }
__device__ __forceinline__ float ntldv(const float* p, size_t i) {
    return __builtin_nontemporal_load(p + i);
}
__device__ __forceinline__ float ntldv(const unsigned short* p, size_t i) {
    return bf2f(__builtin_nontemporal_load(p + i));
}
__device__ __forceinline__ void stv(float* p, size_t i, float v) { p[i] = v; }
__device__ __forceinline__ void stv(unsigned short* p, size_t i, float v) { p[i] = f2bf(v); }

// Opaque redefinition: breaks the value's provenance so the compiler cannot
// rematerialize it from the original global load; it must stay resident.
// R9 evidence: lands in the AGPR half of the unified file (VGPR_Count stays 64).
__device__ __forceinline__ void pin_frag(frag8& f) {
    ui4 t = __builtin_bit_cast(ui4, f);
    asm volatile("" : "+v"(t));
    f = __builtin_bit_cast(frag8, t);
}

// flag=1 => buffers are fp32, flag=0 => bf16. Integer-only tests (fast-math safe).
__global__ void detect_dtype(const unsigned short* __restrict__ w, int* flag) {
    __shared__ int zc, bc;
    if (threadIdx.x == 0) { zc = 0; bc = 0; }
    __syncthreads();
    int z = 0, b = 0;
    for (int i = threadIdx.x; i < 2048; i += 256) {
        unsigned short lo = w[2 * i];            // fp32: low mantissa half / bf16: a value
        if (lo == 0) z++;                        // bf16-rounded fp32 storage => all zero
        unsigned e = (lo >> 7) & 0xFFu;          // bf16 exponent field
        if (e >= 0x86u) b++;                     // |x|>=128 or NaN: impossible for N(0,.05) bf16
    }
    atomicAdd(&zc, z); atomicAdd(&bc, b);
    __syncthreads();
    if (threadIdx.x == 0) *flag = (bc > 0 || zc > 512) ? 1 : 0;
}

// Repack w_hh (256x768) and w_gate||w_map (256x512) into bf16 MFMA B-fragment
// order: frag f=jt*KC+kc; elem[(f*64+lane)*8+j] = W[kc*32+(lane>>4)*8+j][jt*16+(lane&15)]
// Tail threads build wihG[10][768] = fp32(w_ih + b_ih) folded table.
template <typename T>
__global__ void repack_weights(const T* __restrict__ w_hh,
                               const T* __restrict__ w_gate,
                               const T* __restrict__ w_map,
                               const T* __restrict__ w_ih,
                               const T* __restrict__ b_ih,
                               unsigned short* __restrict__ whh_p,
                               unsigned short* __restrict__ wgm_p,
                               float* __restrict__ wihG,
                               const int* __restrict__ flag, int want) {
    if (*flag != want) return;
    int t = blockIdx.x * blockDim.x + threadIdx.x;
    int lane = t & 63;
    int frag = t >> 6;                  // 0..759
    int kbase = (lane >> 4) * 8;
    if (frag < NT1 * KC) {
        int jt = frag / KC, kc = frag % KC;
        int col = jt * 16 + (lane & 15);
        unsigned short* dst = whh_p + ((size_t)frag * 64 + lane) * 8;
        #pragma unroll
        for (int j = 0; j < 8; ++j)
            dst[j] = f2bf(ldv(w_hh, (size_t)(kc * 32 + kbase + j) * 768 + col));
    } else if (frag < (NT1 + NT2) * KC) {
        int f2 = frag - NT1 * KC;
        int jt = f2 / KC, kc = f2 % KC;
        int col = jt * 16 + (lane & 15);
        unsigned short* dst = wgm_p + ((size_t)f2 * 64 + lane) * 8;
        #pragma unroll
        for (int j = 0; j < 8; ++j) {
            int k = kc * 32 + kbase + j;
            dst[j] = f2bf((col < HH) ? ldv(w_gate, (size_t)k * HH + col)
                                     : ldv(w_map, (size_t)k * HH + (col - HH)));
        }
    } else {
        int idx = t - (NT1 + NT2) * KC * 64;     // 0..7679 with grid=190
        if (idx < VV * 768) {
            int c = idx % 768;
            wihG[idx] = ldv(w_ih, (size_t)idx) + ldv(b_ih, (size_t)c);
        }
    }
}

template <typename T>
__global__ __launch_bounds__(1024, 4) void vae_main(
    const T* __restrict__ adj,
    const int* __restrict__ ntypes,
    const T* __restrict__ b_hh,
    const T* __restrict__ b_gate,
    const T* __restrict__ w_mu,
    const T* __restrict__ b_mu,
    const T* __restrict__ w_std,
    const T* __restrict__ b_std,
    const unsigned short* __restrict__ whh_p,
    const unsigned short* __restrict__ wgm_p,
    const float* __restrict__ wihG,
    T* __restrict__ out,
    const int* __restrict__ flag, int want)
{
    if (*flag != want) return;

    __shared__ __align__(16) unsigned short gmAll[BT][NN][HH]; // gm state (128 KB)
    __shared__ __align__(16) unsigned short aggbf[16][264];    // MFMA A src rows 0..7
    __shared__ __align__(16) unsigned short hnew[16][264];     // MFMA A src rows 0..7
    __shared__ unsigned int  amask[BT][NN];                    // adj bitmasks (1 KB)
    __shared__ int           ntva[BT][NN];                     // node types (1 KB)
    __shared__ __align__(16) float bhhL[768];                  // b_hh (3 KB)
    __shared__ float bgL[HH];                                  // b_gate (1 KB)

    // fp32 agg overlays the dead rows 8..15 (those MFMA C-rows are discarded;
    // garbage A-rows 8..15 only pollute discarded C-rows 8..15).
    float* const aggA = (float*)&aggbf[8][0];   // bi 0..3: 4x256 fp32 (4 KB)
    float* const aggB = (float*)&hnew[8][0];    // bi 4..7

    const int tid  = threadIdx.x;
    const int lane = tid & 63;
    const int w    = tid >> 6;          // wave 0..15
    const int b0   = blockIdx.x * BT;

    const frag8* whh8 = (const frag8*)whh_p;
    const frag8* wgm8 = (const frag8*)wgm_p;

    // ---- one-time preload ----
    if (tid < 256) {                         // adj -> bitmask (adj is exactly {0,1})
        int bi = tid >> 5, vv = tid & 31;
        unsigned m = 0;
        for (int n = 0; n < NN; ++n)
            if (ntldv(adj, ((size_t)(b0 + bi) * NN + n) * NN + vv) != 0.0f) m |= (1u << n);
        amask[bi][vv] = m;
    } else if (tid < 512) {
        int idx = tid - 256;
        int bi = idx >> 5, vv = idx & 31;
        ntva[bi][vv] = ntypes[(b0 + bi) * NN + vv];
    }
    for (int i = tid; i < 768; i += 1024) bhhL[i] = ldv(b_hh, i);
    if (tid < HH) bgL[tid] = ldv(b_gate, tid);

    // ---- pin phase-D tiles in regs for all 32 steps (64 regs -> AGPR half).
    frag8 wG[KC], wM[KC];
    {
        const frag8* pG = wgm8 + (size_t)(w     ) * (KC * 64) + lane;
        const frag8* pM = wgm8 + (size_t)(w + 16) * (KC * 64) + lane;
        #pragma unroll
        for (int kc = 0; kc < KC; ++kc) { wG[kc] = pG[kc * 64]; wM[kc] = pM[kc * 64]; }
        #pragma unroll
        for (int kc = 0; kc < KC; ++kc) { pin_frag(wG[kc]); pin_frag(wM[kc]); }
    }
    __syncthreads();

    // A-partial for batch w (waves 0..7): rows <= v-2 gathered during D(v-1);
    // finish-A adds row v-1 and publishes.
    float pa0 = 0.f, pa1 = 0.f, pa2 = 0.f, pa3 = 0.f;
    const int h4 = lane * 4;

    for (int v = 0; v < NN; ++v) {
        // ---- finish-A (waves 0..7): add newest gm row, publish agg ----
        if (w < BT) {
            const int bi = w;
            if (v > 0 && ((amask[bi][v] >> (v - 1)) & 1u)) {
                const us4 g = *(const us4*)(&gmAll[bi][v - 1][0] + h4);
                pa0 += bf2f(g.x); pa1 += bf2f(g.y);
                pa2 += bf2f(g.z); pa3 += bf2f(g.w);
            }
            float* ap = (bi < 4) ? (aggA + bi * 256) : (aggB + (bi - 4) * 256);
            *(float4*)(ap + h4) = make_float4(pa0, pa1, pa2, pa3);
            ushort4 ab; ab.x = f2bf(pa0); ab.y = f2bf(pa1);
            ab.z = f2bf(pa2); ab.w = f2bf(pa3);
            *(ushort4*)&aggbf[bi][h4] = ab;
        }
        __syncthreads();

        // ---- B: gh = agg @ w_hh (MFMA) fused with GRU elementwise -> hnew
        {
            const int t = w;                             // triplet: cols t, t+16, t+32
            const int col = t * 16 + (lane & 15);
            const int q = lane >> 4;                     // C row = 4q+i, valid q<2

            // issue wihG gathers EARLY so their latency hides under the MFMAs
            float xr[4], xz[4], xn[4];
            if (q < 2) {
                #pragma unroll
                for (int i = 0; i < 4; ++i) {
                    const float* wr = wihG + (size_t)ntva[4 * q + i][v] * 768 + col;
                    xr[i] = wr[0]; xz[i] = wr[256]; xn[i] = wr[512];
                }
            }

            facc4 aR = {0.f, 0.f, 0.f, 0.f};
            facc4 aZ = {0.f, 0.f, 0.f, 0.f};
            facc4 aN = {0.f, 0.f, 0.f, 0.f};
            const frag8* pR = whh8 + (size_t)(t     ) * (KC * 64) + lane;
            const frag8* pZ = whh8 + (size_t)(t + 16) * (KC * 64) + lane;
            const frag8* pN = whh8 + (size_t)(t + 32) * (KC * 64) + lane;
            #pragma unroll
            for (int kc = 0; kc < KC; ++kc) {            // per-kc afrag: 4 regs live
                const frag8 af = *(const frag8*)&aggbf[lane & 15][kc * 32 + (lane >> 4) * 8];
                aR = __builtin_amdgcn_mfma_f32_16x16x32_bf16(af, pR[kc * 64], aR, 0, 0, 0);
                aZ = __builtin_amdgcn_mfma_f32_16x16x32_bf16(af, pZ[kc * 64], aZ, 0, 0, 0);
                aN = __builtin_amdgcn_mfma_f32_16x16x32_bf16(af, pN[kc * 64], aN, 0, 0, 0);
            }
            if (q < 2) {
                const float bhr = bhhL[col], bhz = bhhL[col + 256], bhn = bhhL[col + 512];
                const float* ap = (q == 0) ? aggA : aggB;
                #pragma unroll
                for (int i = 0; i < 4; ++i) {
                    const float r = sigm(xr[i] + aR[i] + bhr);
                    const float z = sigm(xz[i] + aZ[i] + bhz);
                    const float n = tanhf(xn[i] + r * (aN[i] + bhn));
                    hnew[4 * q + i][col] = f2bf((1.f - z) * n + z * ap[i * 256 + col]);
                }
            }
        }
        __syncthreads();

        // ---- D: gm_v (pinned wG/wM: zero global traffic) + overlapped
        //      A-gather for step v+1 (waves 0..7; rows <= v-1, no conflict
        //      with D's row-v writes; ds_reads fill MFMA waitcnt gaps).
        {
            facc4 aG = {0.f, 0.f, 0.f, 0.f};
            facc4 aM = {0.f, 0.f, 0.f, 0.f};
            #pragma unroll
            for (int kc = 0; kc < KC; ++kc) {            // per-kc hfrag: 4 regs live
                const frag8 hf = *(const frag8*)&hnew[lane & 15][kc * 32 + (lane >> 4) * 8];
                aG = __builtin_amdgcn_mfma_f32_16x16x32_bf16(hf, wG[kc], aG, 0, 0, 0);
                aM = __builtin_amdgcn_mfma_f32_16x16x32_bf16(hf, wM[kc], aM, 0, 0, 0);
            }
            const int col = w * 16 + (lane & 15);        // 0..255
            const int q = lane >> 4;
            if (q < 2) {
                const float bg = bgL[col];
                #pragma unroll
                for (int i = 0; i < 4; ++i)
                    gmAll[4 * q + i][v][col] = f2bf(sigm(aG[i] + bg) * aM[i]);
            }

            pa0 = pa1 = pa2 = pa3 = 0.f;
            if (w < BT && v + 1 < NN) {
                unsigned m = amask[w][v + 1] & ((v > 0) ? ((1u << v) - 1u) : 0u);
                const unsigned short* rb = &gmAll[w][0][0] + h4;
                while (m) {                  // 2-wide to keep 2 ds_reads in flight
                    const int n0 = __builtin_ctz(m); m &= m - 1;
                    const us4 g0 = *(const us4*)(rb + n0 * HH);
                    if (m) {
                        const int n1 = __builtin_ctz(m); m &= m - 1;
                        const us4 g1 = *(const us4*)(rb + n1 * HH);
                        pa0 += bf2f(g0.x) + bf2f(g1.x);
                        pa1 += bf2f(g0.y) + bf2f(g1.y);
                        pa2 += bf2f(g0.z) + bf2f(g1.z);
                        pa3 += bf2f(g0.w) + bf2f(g1.w);
                    } else {
                        pa0 += bf2f(g0.x); pa1 += bf2f(g0.y);
                        pa2 += bf2f(g0.z); pa3 += bf2f(g0.w);
                    }
                }
            }
        }
        __syncthreads();   // gmAll row v / hnew ready for next finish-A / epilogue
    }

    // ---- Epilogue: hg = h_new(v=31) (in hnew LDS); mu/sigma = hg@w_mu/std + b
    {
        const int bi = w >> 1, half = w & 1, z = lane;   // 2 waves per batch
        float am = 0.f, as = 0.f;
        const int h0 = half * 128;
        #pragma unroll 4
        for (int h = h0; h < h0 + 128; ++h) {
            const float hv = bf2f(hnew[bi][h]);          // LDS broadcast
            am += hv * ldv(w_mu, (size_t)h * ZZ + z);
            as += hv * ldv(w_std, (size_t)h * ZZ + z);
        }
        float* sc = (bi < 4) ? (aggA + bi * 256) : (aggB + (bi - 4) * 256);
        sc[half * 64 + z]       = am;                    // overlay region as scratch
        sc[128 + half * 64 + z] = as;
    }
    __syncthreads();
    if (w < BT) {
        const int bi = w, z = lane;
        const float* sc = (bi < 4) ? (aggA + bi * 256) : (aggB + (bi - 4) * 256);
        const float am = sc[z] + sc[64 + z] + ldv(b_mu, z);
        const float as = sc[128 + z] + sc[192 + z] + ldv(b_std, z);
        stv(out, (size_t)(b0 + bi) * ZZ + z, am);
        stv(out, (size_t)BB * ZZ + (size_t)(b0 + bi) * ZZ + z, as);
    }
}

extern "C" void kernel_launch(void* const* d_in, const int* in_sizes, int n_in,
                              void* d_out, int out_size, void* d_ws, size_t ws_size,
                              hipStream_t stream)
{
    unsigned short* whh_p = (unsigned short*)d_ws;
    unsigned short* wgm_p = whh_p + WHH_ELEMS;
    float* wihG = (float*)(wgm_p + WGM_ELEMS);             // byte off 655360 (16B aligned)

    // dtype flag lives in the last aligned 4 bytes of ws
    size_t flag_off = (ws_size >= 8) ? ((ws_size - 4) & ~(size_t)3) : 0;
    int* flag = (int*)((char*)d_ws + flag_off);

    detect_dtype<<<dim3(1), 256, 0, stream>>>((const unsigned short*)d_in[2], flag);

    // 190 blocks = 640 weight frags * 64 lanes + 7680 wihG elems, exactly
    repack_weights<float><<<dim3(190), 256, 0, stream>>>(
        (const float*)d_in[3], (const float*)d_in[6], (const float*)d_in[8],
        (const float*)d_in[2], (const float*)d_in[4],
        whh_p, wgm_p, wihG, flag, 1);
    repack_weights<unsigned short><<<dim3(190), 256, 0, stream>>>(
        (const unsigned short*)d_in[3], (const unsigned short*)d_in[6],
        (const unsigned short*)d_in[8], (const unsigned short*)d_in[2],
        (const unsigned short*)d_in[4],
        whh_p, wgm_p, wihG, flag, 0);

    vae_main<float><<<dim3(BB / BT), 1024, 0, stream>>>(
        (const float*)d_in[0], (const int*)d_in[1],
        (const float*)d_in[5], (const float*)d_in[7],
        (const float*)d_in[9], (const float*)d_in[10],
        (const float*)d_in[11], (const float*)d_in[12],
        whh_p, wgm_p, wihG, (float*)d_out, flag, 1);
    vae_main<unsigned short><<<dim3(BB / BT), 1024, 0, stream>>>(
        (const unsigned short*)d_in[0], (const int*)d_in[1],
        (const unsigned short*)d_in[5], (const unsigned short*)d_in[7],
        (const unsigned short*)d_in[9], (const unsigned short*)d_in[10],
        (const unsigned short*)d_in[11], (const unsigned short*)d_in[12],
        whh_p, wgm_p, wihG, (unsigned short*)d_out, flag, 0);
}

// Round 9
// 539.399 us; speedup vs baseline: 1.1942x; 1.0008x over previous
//
#include <hip/hip_runtime.h>

// LogicVAE: graph-GRU VAE encoder. B=2048,N=32,V=10,H=256,Z=64.
// gm[b,n] = sigmoid(h@w_gate+b_gate)*(h@w_map) is a pure function of the FINAL
// hidden[b,n] (adj strictly upper-tri), so it's computed once per node.
// R14 = byte-exact R9 (best: 456us steady) + tanhf -> __expf identity.
// Why: R13 proved R9 sits exactly at the 16-wave register budget (64 VGPR +
// 64 pinned AGPR = 128); ANY added live state (pa-carry, early-x) silently
// evicts the wG/wM pins (FETCH 1.177->1.372 GB, dur 456->473). So revert all
// R13 deltas. The one remaining unexplained counter is WRITE ~82MB (~320
// B/thread scratch; only ~1MB of real stores) -- the only libcall in the
// kernel is tanhf (__ocml_tanh_f32). Replace with tanh(x)=1-2/(e^{2x}+1)
// (__expf-based, exact at +-inf, ~1e-6 rel err << bf16 storage error).
// If WRITE collapses -> scratch source found, L2 churn drops, dur improves.
// If counters bit-match R9 -> every term is accounted; roofline next.

#define BB 2048
#define NN 32
#define VV 10
#define HH 256
#define ZZ 64
#define BT 8      // batches per block
#define KC 8      // K chunks: 256/32
#define NT1 48    // 768/16 col tiles (w_hh)
#define NT2 32    // 512/16 col tiles (w_gate||w_map)
#define WHH_ELEMS (NT1 * KC * 64 * 8)             // 196608 ushorts (384 KB)
#define WGM_ELEMS (NT2 * KC * 64 * 8)             // 131072 ushorts (256 KB)

typedef __attribute__((ext_vector_type(8))) short frag8;            // 8 bf16 (4 VGPR)
typedef __attribute__((ext_vector_type(4))) float facc4;            // MFMA accum
typedef __attribute__((ext_vector_type(4))) unsigned short us4;     // 8B LDS load
typedef __attribute__((ext_vector_type(4))) unsigned int ui4;       // asm-pin carrier

__device__ __forceinline__ float bf2f(unsigned short u) {
    unsigned int x = ((unsigned int)u) << 16;
    return __builtin_bit_cast(float, x);
}
__device__ __forceinline__ unsigned short f2bf(float f) {
    unsigned int x = __builtin_bit_cast(unsigned int, f);
    x += 0x7FFFu + ((x >> 16) & 1u);
    return (unsigned short)(x >> 16);
}
__device__ __forceinline__ float sigm(float x) { return 1.0f / (1.0f + __expf(-x)); }
// tanh via exp: exact at +-inf (e->inf: 1; e->0: -1); ~1e-6 rel error.
// Replaces the only libcall (__ocml_tanh_f32) -- candidate scratch source.
__device__ __forceinline__ float tanh_fast(float x) {
    const float e = __expf(2.0f * x);
    return 1.0f - 2.0f / (e + 1.0f);
}
__device__ __forceinline__ float ldv(const float* p, size_t i) { return p[i]; }
__device__ __forceinline__ float ldv(const unsigned short* p, size_t i) { return bf2f(p[i]); }
__device__ __forceinline__ void stv(float* p, size_t i, float v) { p[i] = v; }
__device__ __forceinline__ void stv(unsigned short* p, size_t i, float v) { p[i] = f2bf(v); }

// Opaque redefinition: breaks the value's provenance so the compiler cannot
// rematerialize it from the original global load; it must stay resident.
// R9 evidence: lands in the AGPR half of the unified file (VGPR_Count stays 64).
__device__ __forceinline__ void pin_frag(frag8& f) {
    ui4 t = __builtin_bit_cast(ui4, f);
    asm volatile("" : "+v"(t));
    f = __builtin_bit_cast(frag8, t);
}

// flag=1 => buffers are fp32, flag=0 => bf16. Integer-only tests (fast-math safe).
__global__ void detect_dtype(const unsigned short* __restrict__ w, int* flag) {
    __shared__ int zc, bc;
    if (threadIdx.x == 0) { zc = 0; bc = 0; }
    __syncthreads();
    int z = 0, b = 0;
    for (int i = threadIdx.x; i < 2048; i += 256) {
        unsigned short lo = w[2 * i];            // fp32: low mantissa half / bf16: a value
        if (lo == 0) z++;                        // bf16-rounded fp32 storage => all zero
        unsigned e = (lo >> 7) & 0xFFu;          // bf16 exponent field
        if (e >= 0x86u) b++;                     // |x|>=128 or NaN: impossible for N(0,.05) bf16
    }
    atomicAdd(&zc, z); atomicAdd(&bc, b);
    __syncthreads();
    if (threadIdx.x == 0) *flag = (bc > 0 || zc > 512) ? 1 : 0;
}

// Repack w_hh (256x768) and w_gate||w_map (256x512) into bf16 MFMA B-fragment
// order: frag f=jt*KC+kc; elem[(f*64+lane)*8+j] = W[kc*32+(lane>>4)*8+j][jt*16+(lane&15)]
// Tail threads build wihG[10][768] = fp32(w_ih + b_ih) folded table.
template <typename T>
__global__ void repack_weights(const T* __restrict__ w_hh,
                               const T* __restrict__ w_gate,
                               const T* __restrict__ w_map,
                               const T* __restrict__ w_ih,
                               const T* __restrict__ b_ih,
                               unsigned short* __restrict__ whh_p,
                               unsigned short* __restrict__ wgm_p,
                               float* __restrict__ wihG,
                               const int* __restrict__ flag, int want) {
    if (*flag != want) return;
    int t = blockIdx.x * blockDim.x + threadIdx.x;
    int lane = t & 63;
    int frag = t >> 6;                  // 0..759
    int kbase = (lane >> 4) * 8;
    if (frag < NT1 * KC) {
        int jt = frag / KC, kc = frag % KC;
        int col = jt * 16 + (lane & 15);
        unsigned short* dst = whh_p + ((size_t)frag * 64 + lane) * 8;
        #pragma unroll
        for (int j = 0; j < 8; ++j)
            dst[j] = f2bf(ldv(w_hh, (size_t)(kc * 32 + kbase + j) * 768 + col));
    } else if (frag < (NT1 + NT2) * KC) {
        int f2 = frag - NT1 * KC;
        int jt = f2 / KC, kc = f2 % KC;
        int col = jt * 16 + (lane & 15);
        unsigned short* dst = wgm_p + ((size_t)f2 * 64 + lane) * 8;
        #pragma unroll
        for (int j = 0; j < 8; ++j) {
            int k = kc * 32 + kbase + j;
            dst[j] = f2bf((col < HH) ? ldv(w_gate, (size_t)k * HH + col)
                                     : ldv(w_map, (size_t)k * HH + (col - HH)));
        }
    } else {
        int idx = t - (NT1 + NT2) * KC * 64;     // 0..7679 with grid=190
        if (idx < VV * 768) {
            int c = idx % 768;
            wihG[idx] = ldv(w_ih, (size_t)idx) + ldv(b_ih, (size_t)c);
        }
    }
}

template <typename T>
__global__ __launch_bounds__(1024, 4) void vae_main(
    const T* __restrict__ adj,
    const int* __restrict__ ntypes,
    const T* __restrict__ b_hh,
    const T* __restrict__ b_gate,
    const T* __restrict__ w_mu,
    const T* __restrict__ b_mu,
    const T* __restrict__ w_std,
    const T* __restrict__ b_std,
    const unsigned short* __restrict__ whh_p,
    const unsigned short* __restrict__ wgm_p,
    const float* __restrict__ wihG,
    T* __restrict__ out,
    const int* __restrict__ flag, int want)
{
    if (*flag != want) return;

    __shared__ __align__(16) unsigned short gmAll[BT][NN][HH]; // gm state (128 KB)
    __shared__ __align__(16) unsigned short aggbf[16][264];    // MFMA A src rows 0..7
    __shared__ __align__(16) unsigned short hnew[16][264];     // MFMA A src rows 0..7
    __shared__ unsigned int  amask[BT][NN];                    // adj bitmasks (1 KB)
    __shared__ int           ntva[BT][NN];                     // node types (1 KB)
    __shared__ __align__(16) float bhhL[768];                  // b_hh (3 KB)
    __shared__ float bgL[HH];                                  // b_gate (1 KB)

    // fp32 agg overlays the dead rows 8..15 (those MFMA C-rows are discarded;
    // garbage A-rows 8..15 only pollute discarded C-rows 8..15).
    float* const aggA = (float*)&aggbf[8][0];   // bi 0..3: 4x256 fp32 (4 KB)
    float* const aggB = (float*)&hnew[8][0];    // bi 4..7

    const int tid  = threadIdx.x;
    const int lane = tid & 63;
    const int w    = tid >> 6;          // wave 0..15
    const int b0   = blockIdx.x * BT;

    const frag8* whh8 = (const frag8*)whh_p;
    const frag8* wgm8 = (const frag8*)wgm_p;

    // ---- one-time preload ----
    if (tid < 256) {                         // adj -> bitmask (adj is exactly {0,1})
        int bi = tid >> 5, vv = tid & 31;
        unsigned m = 0;
        for (int n = 0; n < NN; ++n)
            if (ldv(adj, ((size_t)(b0 + bi) * NN + n) * NN + vv) != 0.0f) m |= (1u << n);
        amask[bi][vv] = m;
    } else if (tid < 512) {
        int idx = tid - 256;
        int bi = idx >> 5, vv = idx & 31;
        ntva[bi][vv] = ntypes[(b0 + bi) * NN + vv];
    }
    for (int i = tid; i < 768; i += 1024) bhhL[i] = ldv(b_hh, i);
    if (tid < HH) bgL[tid] = ldv(b_gate, tid);

    // ---- pin phase-D tiles in regs for all 32 steps (64 regs -> AGPR half).
    //      asm redefinition makes them non-rematerializable.
    frag8 wG[KC], wM[KC];
    {
        const frag8* pG = wgm8 + (size_t)(w     ) * (KC * 64) + lane;
        const frag8* pM = wgm8 + (size_t)(w + 16) * (KC * 64) + lane;
        #pragma unroll
        for (int kc = 0; kc < KC; ++kc) { wG[kc] = pG[kc * 64]; wM[kc] = pM[kc * 64]; }
        #pragma unroll
        for (int kc = 0; kc < KC; ++kc) { pin_frag(wG[kc]); pin_frag(wM[kc]); }
    }
    __syncthreads();

    for (int v = 0; v < NN; ++v) {
        // ---- A (waves 0..7): agg over neighbor gm rows, all from LDS.
        if (w < BT) {
            const int bi = w;
            const int h4 = lane * 4;
            unsigned m = amask[bi][v];       // wave-uniform
            float a0 = 0.f, a1 = 0.f, a2 = 0.f, a3 = 0.f;
            const unsigned short* rb = &gmAll[bi][0][0] + h4;
            while (m) {                      // 2-wide to keep 2 ds_reads in flight
                const int n0 = __builtin_ctz(m); m &= m - 1;
                const us4 g0 = *(const us4*)(rb + n0 * HH);
                if (m) {
                    const int n1 = __builtin_ctz(m); m &= m - 1;
                    const us4 g1 = *(const us4*)(rb + n1 * HH);
                    a0 += bf2f(g0.x) + bf2f(g1.x);
                    a1 += bf2f(g0.y) + bf2f(g1.y);
                    a2 += bf2f(g0.z) + bf2f(g1.z);
                    a3 += bf2f(g0.w) + bf2f(g1.w);
                } else {
                    a0 += bf2f(g0.x); a1 += bf2f(g0.y);
                    a2 += bf2f(g0.z); a3 += bf2f(g0.w);
                }
            }
            float* ap = (bi < 4) ? (aggA + bi * 256) : (aggB + (bi - 4) * 256);
            *(float4*)(ap + h4) = make_float4(a0, a1, a2, a3);
            ushort4 ab; ab.x = f2bf(a0); ab.y = f2bf(a1); ab.z = f2bf(a2); ab.w = f2bf(a3);
            *(ushort4*)&aggbf[bi][h4] = ab;
        }
        __syncthreads();

        // ---- B: gh = agg @ w_hh (MFMA) fused with GRU elementwise -> hnew
        {
            const int t = w;                             // triplet: cols t, t+16, t+32
            const int col = t * 16 + (lane & 15);
            const int q = lane >> 4;                     // C row = 4q+i, valid q<2

            facc4 aR = {0.f, 0.f, 0.f, 0.f};
            facc4 aZ = {0.f, 0.f, 0.f, 0.f};
            facc4 aN = {0.f, 0.f, 0.f, 0.f};
            const frag8* pR = whh8 + (size_t)(t     ) * (KC * 64) + lane;
            const frag8* pZ = whh8 + (size_t)(t + 16) * (KC * 64) + lane;
            const frag8* pN = whh8 + (size_t)(t + 32) * (KC * 64) + lane;
            #pragma unroll
            for (int kc = 0; kc < KC; ++kc) {            // per-kc afrag: 4 regs live
                const frag8 af = *(const frag8*)&aggbf[lane & 15][kc * 32 + (lane >> 4) * 8];
                aR = __builtin_amdgcn_mfma_f32_16x16x32_bf16(af, pR[kc * 64], aR, 0, 0, 0);
                aZ = __builtin_amdgcn_mfma_f32_16x16x32_bf16(af, pZ[kc * 64], aZ, 0, 0, 0);
                aN = __builtin_amdgcn_mfma_f32_16x16x32_bf16(af, pN[kc * 64], aN, 0, 0, 0);
            }
            if (q < 2) {
                const float bhr = bhhL[col], bhz = bhhL[col + 256], bhn = bhhL[col + 512];
                const float* ap = (q == 0) ? aggA : aggB;
                #pragma unroll
                for (int i = 0; i < 4; ++i) {
                    const float* wr = wihG + (size_t)ntva[4 * q + i][v] * 768 + col;
                    const float r = sigm(wr[0]   + aR[i] + bhr);
                    const float z = sigm(wr[256] + aZ[i] + bhz);
                    const float n = tanh_fast(wr[512] + r * (aN[i] + bhn));
                    hnew[4 * q + i][col] = f2bf((1.f - z) * n + z * ap[i * 256 + col]);
                }
            }
        }
        __syncthreads();

        // ---- D: gm_v = sigmoid(h@w_gate+b_gate) * (h@w_map) -> gmAll[.][v]
        //      (wG/wM pinned in registers: zero global traffic in this phase)
        {
            facc4 aG = {0.f, 0.f, 0.f, 0.f};
            facc4 aM = {0.f, 0.f, 0.f, 0.f};
            #pragma unroll
            for (int kc = 0; kc < KC; ++kc) {            // per-kc hfrag: 4 regs live
                const frag8 hf = *(const frag8*)&hnew[lane & 15][kc * 32 + (lane >> 4) * 8];
                aG = __builtin_amdgcn_mfma_f32_16x16x32_bf16(hf, wG[kc], aG, 0, 0, 0);
                aM = __builtin_amdgcn_mfma_f32_16x16x32_bf16(hf, wM[kc], aM, 0, 0, 0);
            }
            const int col = w * 16 + (lane & 15);        // 0..255
            const int q = lane >> 4;
            if (q < 2) {
                const float bg = bgL[col];
                #pragma unroll
                for (int i = 0; i < 4; ++i)
                    gmAll[4 * q + i][v][col] = f2bf(sigm(aG[i] + bg) * aM[i]);
            }
        }
        __syncthreads();   // gmAll row v / hnew ready for next step's A / epilogue
    }

    // ---- Epilogue: hg = h_new(v=31) (in hnew LDS); mu/sigma = hg@w_mu/std + b
    {
        const int bi = w >> 1, half = w & 1, z = lane;   // 2 waves per batch
        float am = 0.f, as = 0.f;
        const int h0 = half * 128;
        #pragma unroll 4
        for (int h = h0; h < h0 + 128; ++h) {
            const float hv = bf2f(hnew[bi][h]);          // LDS broadcast
            am += hv * ldv(w_mu, (size_t)h * ZZ + z);
            as += hv * ldv(w_std, (size_t)h * ZZ + z);
        }
        float* sc = (bi < 4) ? (aggA + bi * 256) : (aggB + (bi - 4) * 256);
        sc[half * 64 + z]       = am;                    // overlay region as scratch
        sc[128 + half * 64 + z] = as;
    }
    __syncthreads();
    if (w < BT) {
        const int bi = w, z = lane;
        const float* sc = (bi < 4) ? (aggA + bi * 256) : (aggB + (bi - 4) * 256);
        const float am = sc[z] + sc[64 + z] + ldv(b_mu, z);
        const float as = sc[128 + z] + sc[192 + z] + ldv(b_std, z);
        stv(out, (size_t)(b0 + bi) * ZZ + z, am);
        stv(out, (size_t)BB * ZZ + (size_t)(b0 + bi) * ZZ + z, as);
    }
}

extern "C" void kernel_launch(void* const* d_in, const int* in_sizes, int n_in,
                              void* d_out, int out_size, void* d_ws, size_t ws_size,
                              hipStream_t stream)
{
    unsigned short* whh_p = (unsigned short*)d_ws;
    unsigned short* wgm_p = whh_p + WHH_ELEMS;
    float* wihG = (float*)(wgm_p + WGM_ELEMS);             // byte off 655360 (16B aligned)

    // dtype flag lives in the last aligned 4 bytes of ws
    size_t flag_off = (ws_size >= 8) ? ((ws_size - 4) & ~(size_t)3) : 0;
    int* flag = (int*)((char*)d_ws + flag_off);

    detect_dtype<<<dim3(1), 256, 0, stream>>>((const unsigned short*)d_in[2], flag);

    // 190 blocks = 640 weight frags * 64 lanes + 7680 wihG elems, exactly
    repack_weights<float><<<dim3(190), 256, 0, stream>>>(
        (const float*)d_in[3], (const float*)d_in[6], (const float*)d_in[8],
        (const float*)d_in[2], (const float*)d_in[4],
        whh_p, wgm_p, wihG, flag, 1);
    repack_weights<unsigned short><<<dim3(190), 256, 0, stream>>>(
        (const unsigned short*)d_in[3], (const unsigned short*)d_in[6],
        (const unsigned short*)d_in[8], (const unsigned short*)d_in[2],
        (const unsigned short*)d_in[4],
        whh_p, wgm_p, wihG, flag, 0);

    vae_main<float><<<dim3(BB / BT), 1024, 0, stream>>>(
        (const float*)d_in[0], (const int*)d_in[1],
        (const float*)d_in[5], (const float*)d_in[7],
        (const float*)d_in[9], (const float*)d_in[10],
        (const float*)d_in[11], (const float*)d_in[12],
        whh_p, wgm_p, wihG, (float*)d_out, flag, 1);
    vae_main<unsigned short><<<dim3(BB / BT), 1024, 0, stream>>>(
        (const unsigned short*)d_in[0], (const int*)d_in[1],
        (const unsigned short*)d_in[5], (const unsigned short*)d_in[7],
        (const unsigned short*)d_in[9], (const unsigned short*)d_in[10],
        (const unsigned short*)d_in[11], (const unsigned short*)d_in[12],
        whh_p, wgm_p, wihG, (unsigned short*)d_out, flag, 0);
}

// Round 10
// 528.381 us; speedup vs baseline: 1.2191x; 1.0209x over previous
//
#include <hip/hip_runtime.h>

// LogicVAE: graph-GRU VAE encoder. B=2048,N=32,V=10,H=256,Z=64.
// gm[b,n] = sigmoid(h@w_gate+b_gate)*(h@w_map) is a pure function of the FINAL
// hidden[b,n] (adj strictly upper-tri), so it's computed once per node.
// R15 = byte-exact R9: the measured optimum (456us steady) after 10
// falsification rounds (R10-R14 all regressed). Final ledger:
//  - 1024 thr / 16 waves / BT=8 / 256 blocks: TLP beats ILP (R11/R12: 8-wave
//    variants 524-580us despite 2x regs); BT=16 idles half the grid (R7).
//  - gmAll[8][32][256] bf16 in LDS (128KB): zero gm global traffic.
//  - wG/wM asm-opaque-pinned: lands in AGPR half of unified file; 64 VGPR +
//    64 AGPR = EXACTLY the 128-reg/16-wave budget. Any extra live state
//    (R13's pa-carry/early-x) or bigger pins (R11) silently evict/spill.
//  - tanhf kept (R14's __expf identity: -66MB FETCH but +14us critical-path
//    VALU -- libcall is cheaper on the serial GRU chain).
// Binding constraint: dur ~= hbm_bytes/2.6TB/s; FETCH ~1.17GB irreducible in
// this structure (whh stream 384KB/block/step, ~35% L2-miss share,
// unexplainable/unfixable within budgets) + ~9us/step phase latency (every
// overlap attempt regressed). This is the structural ceiling.

#define BB 2048
#define NN 32
#define VV 10
#define HH 256
#define ZZ 64
#define BT 8      // batches per block
#define KC 8      // K chunks: 256/32
#define NT1 48    // 768/16 col tiles (w_hh)
#define NT2 32    // 512/16 col tiles (w_gate||w_map)
#define WHH_ELEMS (NT1 * KC * 64 * 8)             // 196608 ushorts (384 KB)
#define WGM_ELEMS (NT2 * KC * 64 * 8)             // 131072 ushorts (256 KB)

typedef __attribute__((ext_vector_type(8))) short frag8;            // 8 bf16 (4 VGPR)
typedef __attribute__((ext_vector_type(4))) float facc4;            // MFMA accum
typedef __attribute__((ext_vector_type(4))) unsigned short us4;     // 8B LDS load
typedef __attribute__((ext_vector_type(4))) unsigned int ui4;       // asm-pin carrier

__device__ __forceinline__ float bf2f(unsigned short u) {
    unsigned int x = ((unsigned int)u) << 16;
    return __builtin_bit_cast(float, x);
}
__device__ __forceinline__ unsigned short f2bf(float f) {
    unsigned int x = __builtin_bit_cast(unsigned int, f);
    x += 0x7FFFu + ((x >> 16) & 1u);
    return (unsigned short)(x >> 16);
}
__device__ __forceinline__ float sigm(float x) { return 1.0f / (1.0f + __expf(-x)); }
__device__ __forceinline__ float ldv(const float* p, size_t i) { return p[i]; }
__device__ __forceinline__ float ldv(const unsigned short* p, size_t i) { return bf2f(p[i]); }
__device__ __forceinline__ void stv(float* p, size_t i, float v) { p[i] = v; }
__device__ __forceinline__ void stv(unsigned short* p, size_t i, float v) { p[i] = f2bf(v); }

// Opaque redefinition: breaks the value's provenance so the compiler cannot
// rematerialize it from the original global load; it must stay resident.
// Lands in the AGPR half of the unified file (VGPR_Count stays 64).
__device__ __forceinline__ void pin_frag(frag8& f) {
    ui4 t = __builtin_bit_cast(ui4, f);
    asm volatile("" : "+v"(t));
    f = __builtin_bit_cast(frag8, t);
}

// flag=1 => buffers are fp32, flag=0 => bf16. Integer-only tests (fast-math safe).
__global__ void detect_dtype(const unsigned short* __restrict__ w, int* flag) {
    __shared__ int zc, bc;
    if (threadIdx.x == 0) { zc = 0; bc = 0; }
    __syncthreads();
    int z = 0, b = 0;
    for (int i = threadIdx.x; i < 2048; i += 256) {
        unsigned short lo = w[2 * i];            // fp32: low mantissa half / bf16: a value
        if (lo == 0) z++;                        // bf16-rounded fp32 storage => all zero
        unsigned e = (lo >> 7) & 0xFFu;          // bf16 exponent field
        if (e >= 0x86u) b++;                     // |x|>=128 or NaN: impossible for N(0,.05) bf16
    }
    atomicAdd(&zc, z); atomicAdd(&bc, b);
    __syncthreads();
    if (threadIdx.x == 0) *flag = (bc > 0 || zc > 512) ? 1 : 0;
}

// Repack w_hh (256x768) and w_gate||w_map (256x512) into bf16 MFMA B-fragment
// order: frag f=jt*KC+kc; elem[(f*64+lane)*8+j] = W[kc*32+(lane>>4)*8+j][jt*16+(lane&15)]
// Tail threads build wihG[10][768] = fp32(w_ih + b_ih) folded table.
template <typename T>
__global__ void repack_weights(const T* __restrict__ w_hh,
                               const T* __restrict__ w_gate,
                               const T* __restrict__ w_map,
                               const T* __restrict__ w_ih,
                               const T* __restrict__ b_ih,
                               unsigned short* __restrict__ whh_p,
                               unsigned short* __restrict__ wgm_p,
                               float* __restrict__ wihG,
                               const int* __restrict__ flag, int want) {
    if (*flag != want) return;
    int t = blockIdx.x * blockDim.x + threadIdx.x;
    int lane = t & 63;
    int frag = t >> 6;                  // 0..759
    int kbase = (lane >> 4) * 8;
    if (frag < NT1 * KC) {
        int jt = frag / KC, kc = frag % KC;
        int col = jt * 16 + (lane & 15);
        unsigned short* dst = whh_p + ((size_t)frag * 64 + lane) * 8;
        #pragma unroll
        for (int j = 0; j < 8; ++j)
            dst[j] = f2bf(ldv(w_hh, (size_t)(kc * 32 + kbase + j) * 768 + col));
    } else if (frag < (NT1 + NT2) * KC) {
        int f2 = frag - NT1 * KC;
        int jt = f2 / KC, kc = f2 % KC;
        int col = jt * 16 + (lane & 15);
        unsigned short* dst = wgm_p + ((size_t)f2 * 64 + lane) * 8;
        #pragma unroll
        for (int j = 0; j < 8; ++j) {
            int k = kc * 32 + kbase + j;
            dst[j] = f2bf((col < HH) ? ldv(w_gate, (size_t)k * HH + col)
                                     : ldv(w_map, (size_t)k * HH + (col - HH)));
        }
    } else {
        int idx = t - (NT1 + NT2) * KC * 64;     // 0..7679 with grid=190
        if (idx < VV * 768) {
            int c = idx % 768;
            wihG[idx] = ldv(w_ih, (size_t)idx) + ldv(b_ih, (size_t)c);
        }
    }
}

template <typename T>
__global__ __launch_bounds__(1024, 4) void vae_main(
    const T* __restrict__ adj,
    const int* __restrict__ ntypes,
    const T* __restrict__ b_hh,
    const T* __restrict__ b_gate,
    const T* __restrict__ w_mu,
    const T* __restrict__ b_mu,
    const T* __restrict__ w_std,
    const T* __restrict__ b_std,
    const unsigned short* __restrict__ whh_p,
    const unsigned short* __restrict__ wgm_p,
    const float* __restrict__ wihG,
    T* __restrict__ out,
    const int* __restrict__ flag, int want)
{
    if (*flag != want) return;

    __shared__ __align__(16) unsigned short gmAll[BT][NN][HH]; // gm state (128 KB)
    __shared__ __align__(16) unsigned short aggbf[16][264];    // MFMA A src rows 0..7
    __shared__ __align__(16) unsigned short hnew[16][264];     // MFMA A src rows 0..7
    __shared__ unsigned int  amask[BT][NN];                    // adj bitmasks (1 KB)
    __shared__ int           ntva[BT][NN];                     // node types (1 KB)
    __shared__ __align__(16) float bhhL[768];                  // b_hh (3 KB)
    __shared__ float bgL[HH];                                  // b_gate (1 KB)

    // fp32 agg overlays the dead rows 8..15 (those MFMA C-rows are discarded;
    // garbage A-rows 8..15 only pollute discarded C-rows 8..15).
    float* const aggA = (float*)&aggbf[8][0];   // bi 0..3: 4x256 fp32 (4 KB)
    float* const aggB = (float*)&hnew[8][0];    // bi 4..7

    const int tid  = threadIdx.x;
    const int lane = tid & 63;
    const int w    = tid >> 6;          // wave 0..15
    const int b0   = blockIdx.x * BT;

    const frag8* whh8 = (const frag8*)whh_p;
    const frag8* wgm8 = (const frag8*)wgm_p;

    // ---- one-time preload ----
    if (tid < 256) {                         // adj -> bitmask (adj is exactly {0,1})
        int bi = tid >> 5, vv = tid & 31;
        unsigned m = 0;
        for (int n = 0; n < NN; ++n)
            if (ldv(adj, ((size_t)(b0 + bi) * NN + n) * NN + vv) != 0.0f) m |= (1u << n);
        amask[bi][vv] = m;
    } else if (tid < 512) {
        int idx = tid - 256;
        int bi = idx >> 5, vv = idx & 31;
        ntva[bi][vv] = ntypes[(b0 + bi) * NN + vv];
    }
    for (int i = tid; i < 768; i += 1024) bhhL[i] = ldv(b_hh, i);
    if (tid < HH) bgL[tid] = ldv(b_gate, tid);

    // ---- pin phase-D tiles in regs for all 32 steps (64 regs -> AGPR half).
    //      asm redefinition makes them non-rematerializable.
    frag8 wG[KC], wM[KC];
    {
        const frag8* pG = wgm8 + (size_t)(w     ) * (KC * 64) + lane;
        const frag8* pM = wgm8 + (size_t)(w + 16) * (KC * 64) + lane;
        #pragma unroll
        for (int kc = 0; kc < KC; ++kc) { wG[kc] = pG[kc * 64]; wM[kc] = pM[kc * 64]; }
        #pragma unroll
        for (int kc = 0; kc < KC; ++kc) { pin_frag(wG[kc]); pin_frag(wM[kc]); }
    }
    __syncthreads();

    for (int v = 0; v < NN; ++v) {
        // ---- A (waves 0..7): agg over neighbor gm rows, all from LDS.
        if (w < BT) {
            const int bi = w;
            const int h4 = lane * 4;
            unsigned m = amask[bi][v];       // wave-uniform
            float a0 = 0.f, a1 = 0.f, a2 = 0.f, a3 = 0.f;
            const unsigned short* rb = &gmAll[bi][0][0] + h4;
            while (m) {                      // 2-wide to keep 2 ds_reads in flight
                const int n0 = __builtin_ctz(m); m &= m - 1;
                const us4 g0 = *(const us4*)(rb + n0 * HH);
                if (m) {
                    const int n1 = __builtin_ctz(m); m &= m - 1;
                    const us4 g1 = *(const us4*)(rb + n1 * HH);
                    a0 += bf2f(g0.x) + bf2f(g1.x);
                    a1 += bf2f(g0.y) + bf2f(g1.y);
                    a2 += bf2f(g0.z) + bf2f(g1.z);
                    a3 += bf2f(g0.w) + bf2f(g1.w);
                } else {
                    a0 += bf2f(g0.x); a1 += bf2f(g0.y);
                    a2 += bf2f(g0.z); a3 += bf2f(g0.w);
                }
            }
            float* ap = (bi < 4) ? (aggA + bi * 256) : (aggB + (bi - 4) * 256);
            *(float4*)(ap + h4) = make_float4(a0, a1, a2, a3);
            ushort4 ab; ab.x = f2bf(a0); ab.y = f2bf(a1); ab.z = f2bf(a2); ab.w = f2bf(a3);
            *(ushort4*)&aggbf[bi][h4] = ab;
        }
        __syncthreads();

        // ---- B: gh = agg @ w_hh (MFMA) fused with GRU elementwise -> hnew
        {
            const int t = w;                             // triplet: cols t, t+16, t+32
            const int col = t * 16 + (lane & 15);
            const int q = lane >> 4;                     // C row = 4q+i, valid q<2

            facc4 aR = {0.f, 0.f, 0.f, 0.f};
            facc4 aZ = {0.f, 0.f, 0.f, 0.f};
            facc4 aN = {0.f, 0.f, 0.f, 0.f};
            const frag8* pR = whh8 + (size_t)(t     ) * (KC * 64) + lane;
            const frag8* pZ = whh8 + (size_t)(t + 16) * (KC * 64) + lane;
            const frag8* pN = whh8 + (size_t)(t + 32) * (KC * 64) + lane;
            #pragma unroll
            for (int kc = 0; kc < KC; ++kc) {            // per-kc afrag: 4 regs live
                const frag8 af = *(const frag8*)&aggbf[lane & 15][kc * 32 + (lane >> 4) * 8];
                aR = __builtin_amdgcn_mfma_f32_16x16x32_bf16(af, pR[kc * 64], aR, 0, 0, 0);
                aZ = __builtin_amdgcn_mfma_f32_16x16x32_bf16(af, pZ[kc * 64], aZ, 0, 0, 0);
                aN = __builtin_amdgcn_mfma_f32_16x16x32_bf16(af, pN[kc * 64], aN, 0, 0, 0);
            }
            if (q < 2) {
                const float bhr = bhhL[col], bhz = bhhL[col + 256], bhn = bhhL[col + 512];
                const float* ap = (q == 0) ? aggA : aggB;
                #pragma unroll
                for (int i = 0; i < 4; ++i) {
                    const float* wr = wihG + (size_t)ntva[4 * q + i][v] * 768 + col;
                    const float r = sigm(wr[0]   + aR[i] + bhr);
                    const float z = sigm(wr[256] + aZ[i] + bhz);
                    const float n = tanhf(wr[512] + r * (aN[i] + bhn));
                    hnew[4 * q + i][col] = f2bf((1.f - z) * n + z * ap[i * 256 + col]);
                }
            }
        }
        __syncthreads();

        // ---- D: gm_v = sigmoid(h@w_gate+b_gate) * (h@w_map) -> gmAll[.][v]
        //      (wG/wM pinned in registers: zero global traffic in this phase)
        {
            facc4 aG = {0.f, 0.f, 0.f, 0.f};
            facc4 aM = {0.f, 0.f, 0.f, 0.f};
            #pragma unroll
            for (int kc = 0; kc < KC; ++kc) {            // per-kc hfrag: 4 regs live
                const frag8 hf = *(const frag8*)&hnew[lane & 15][kc * 32 + (lane >> 4) * 8];
                aG = __builtin_amdgcn_mfma_f32_16x16x32_bf16(hf, wG[kc], aG, 0, 0, 0);
                aM = __builtin_amdgcn_mfma_f32_16x16x32_bf16(hf, wM[kc], aM, 0, 0, 0);
            }
            const int col = w * 16 + (lane & 15);        // 0..255
            const int q = lane >> 4;
            if (q < 2) {
                const float bg = bgL[col];
                #pragma unroll
                for (int i = 0; i < 4; ++i)
                    gmAll[4 * q + i][v][col] = f2bf(sigm(aG[i] + bg) * aM[i]);
            }
        }
        __syncthreads();   // gmAll row v / hnew ready for next step's A / epilogue
    }

    // ---- Epilogue: hg = h_new(v=31) (in hnew LDS); mu/sigma = hg@w_mu/std + b
    {
        const int bi = w >> 1, half = w & 1, z = lane;   // 2 waves per batch
        float am = 0.f, as = 0.f;
        const int h0 = half * 128;
        #pragma unroll 4
        for (int h = h0; h < h0 + 128; ++h) {
            const float hv = bf2f(hnew[bi][h]);          // LDS broadcast
            am += hv * ldv(w_mu, (size_t)h * ZZ + z);
            as += hv * ldv(w_std, (size_t)h * ZZ + z);
        }
        float* sc = (bi < 4) ? (aggA + bi * 256) : (aggB + (bi - 4) * 256);
        sc[half * 64 + z]       = am;                    // overlay region as scratch
        sc[128 + half * 64 + z] = as;
    }
    __syncthreads();
    if (w < BT) {
        const int bi = w, z = lane;
        const float* sc = (bi < 4) ? (aggA + bi * 256) : (aggB + (bi - 4) * 256);
        const float am = sc[z] + sc[64 + z] + ldv(b_mu, z);
        const float as = sc[128 + z] + sc[192 + z] + ldv(b_std, z);
        stv(out, (size_t)(b0 + bi) * ZZ + z, am);
        stv(out, (size_t)BB * ZZ + (size_t)(b0 + bi) * ZZ + z, as);
    }
}

extern "C" void kernel_launch(void* const* d_in, const int* in_sizes, int n_in,
                              void* d_out, int out_size, void* d_ws, size_t ws_size,
                              hipStream_t stream)
{
    unsigned short* whh_p = (unsigned short*)d_ws;
    unsigned short* wgm_p = whh_p + WHH_ELEMS;
    float* wihG = (float*)(wgm_p + WGM_ELEMS);             // byte off 655360 (16B aligned)

    // dtype flag lives in the last aligned 4 bytes of ws
    size_t flag_off = (ws_size >= 8) ? ((ws_size - 4) & ~(size_t)3) : 0;
    int* flag = (int*)((char*)d_ws + flag_off);

    detect_dtype<<<dim3(1), 256, 0, stream>>>((const unsigned short*)d_in[2], flag);

    // 190 blocks = 640 weight frags * 64 lanes + 7680 wihG elems, exactly
    repack_weights<float><<<dim3(190), 256, 0, stream>>>(
        (const float*)d_in[3], (const float*)d_in[6], (const float*)d_in[8],
        (const float*)d_in[2], (const float*)d_in[4],
        whh_p, wgm_p, wihG, flag, 1);
    repack_weights<unsigned short><<<dim3(190), 256, 0, stream>>>(
        (const unsigned short*)d_in[3], (const unsigned short*)d_in[6],
        (const unsigned short*)d_in[8], (const unsigned short*)d_in[2],
        (const unsigned short*)d_in[4],
        whh_p, wgm_p, wihG, flag, 0);

    vae_main<float><<<dim3(BB / BT), 1024, 0, stream>>>(
        (const float*)d_in[0], (const int*)d_in[1],
        (const float*)d_in[5], (const float*)d_in[7],
        (const float*)d_in[9], (const float*)d_in[10],
        (const float*)d_in[11], (const float*)d_in[12],
        whh_p, wgm_p, wihG, (float*)d_out, flag, 1);
    vae_main<unsigned short><<<dim3(BB / BT), 1024, 0, stream>>>(
        (const unsigned short*)d_in[0], (const int*)d_in[1],
        (const unsigned short*)d_in[5], (const unsigned short*)d_in[7],
        (const unsigned short*)d_in[9], (const unsigned short*)d_in[10],
        (const unsigned short*)d_in[11], (const unsigned short*)d_in[12],
        whh_p, wgm_p, wihG, (unsigned short*)d_out, flag, 0);
}